// Round 2
// baseline (767.338 us; speedup 1.0000x reference)
//
#include <hip/hip_runtime.h>
#include <math.h>

#define PHASE_K  0.3490658503988659f   // PI / 9.0 (= 1/(MARGIN/PI))

// One 64-lane wave per edge. Lane i handles complex dims [4i, 4i+4) of 256.
// No workspace usage: cos/sin computed in-kernel (phases are tiny, |x|<=0.035 rad).
__global__ __launch_bounds__(256) void rotate_score_kernel(
    const float* __restrict__ node,     // [100000, 512]
    const int*   __restrict__ eidx,     // [2, nedges] flat
    const int*   __restrict__ rel,      // [nedges]
    const float* __restrict__ rel_emb,  // [64, 256]
    const float* __restrict__ temp,     // scalar
    const float* __restrict__ bias,     // scalar
    float*       __restrict__ out,      // [nedges]
    int nedges)
{
    int gtid = blockIdx.x * 256 + threadIdx.x;
    int edge = gtid >> 6;
    int lane = threadIdx.x & 63;
    if (edge >= nedges) return;          // whole wave exits together (edge uniform per wave)

    int h = eidx[edge];
    int t = eidx[nedges + edge];
    int r = rel[edge];
    int d = lane << 2;                   // dim offset in [0, 256), step 4

    const float4* ph = (const float4*)(node + (size_t)h * 512 + d);
    const float4* pt = (const float4*)(node + (size_t)t * 512 + d);
    float4 rh = ph[0];                   // re(head)
    float4 ih = ph[64];                  // im(head): +256 floats
    float4 rt = pt[0];
    float4 it = pt[64];
    float4 pe = *(const float4*)(rel_emb + (r << 8) + d);

    float cx, sx, cy, sy, cz, sz, cw, sw;
    sincosf(pe.x * PHASE_K, &sx, &cx);
    sincosf(pe.y * PHASE_K, &sy, &cy);
    sincosf(pe.z * PHASE_K, &sz, &cz);
    sincosf(pe.w * PHASE_K, &sw, &cw);

    float sum;
    {
        float rd, id;
        rd = fmaf(rh.x, cx, -fmaf(ih.x, sx, rt.x));
        id = fmaf(rh.x, sx,  fmaf(ih.x, cx, -it.x));
        sum  = sqrtf(fmaf(rd, rd, id * id));
        rd = fmaf(rh.y, cy, -fmaf(ih.y, sy, rt.y));
        id = fmaf(rh.y, sy,  fmaf(ih.y, cy, -it.y));
        sum += sqrtf(fmaf(rd, rd, id * id));
        rd = fmaf(rh.z, cz, -fmaf(ih.z, sz, rt.z));
        id = fmaf(rh.z, sz,  fmaf(ih.z, cz, -it.z));
        sum += sqrtf(fmaf(rd, rd, id * id));
        rd = fmaf(rh.w, cw, -fmaf(ih.w, sw, rt.w));
        id = fmaf(rh.w, sw,  fmaf(ih.w, cw, -it.w));
        sum += sqrtf(fmaf(rd, rd, id * id));
    }

    // 64-lane butterfly reduction
    #pragma unroll
    for (int m = 1; m < 64; m <<= 1)
        sum += __shfl_xor(sum, m);

    if (lane == 0) {
        float T = temp[0];
        float B = bias[0];
        out[edge] = B - (sum * (1.0f / 256.0f)) / T;
    }
}

extern "C" void kernel_launch(void* const* d_in, const int* in_sizes, int n_in,
                              void* d_out, int out_size, void* d_ws, size_t ws_size,
                              hipStream_t stream) {
    const float* node    = (const float*)d_in[0];
    const int*   eidx    = (const int*)  d_in[1];
    const int*   rel     = (const int*)  d_in[2];
    const float* rel_emb = (const float*)d_in[3];
    const float* temp    = (const float*)d_in[4];
    const float* bias    = (const float*)d_in[5];
    float*       out     = (float*)d_out;

    int nedges = in_sizes[1] / 2;        // edge_index is [2, nedges]

    int blocks = (nedges + 3) / 4;       // 4 waves (edges) per 256-thread block
    rotate_score_kernel<<<blocks, 256, 0, stream>>>(
        node, eidx, rel, rel_emb, temp, bias, out, nedges);
}